// Round 1
// baseline (326.440 us; speedup 1.0000x reference)
//
#include <hip/hip_runtime.h>

#define BB 8
#define TT 2048
#define CC 1024
#define HH 64
#define MM (BB * TT)   // 16384 rows

// ---------------------------------------------------------------------------
// Kernel 1: QKV projection.  out[m,h] = sum_c x[m,c] * W[h,c]
// grid = (MM/64, 3), block = 256 (16x16), per-thread 4x4, K-chunks of 32.
// LDS tiles stored transposed [kk][m] so compute reads are float4 (b128).
// ---------------------------------------------------------------------------
__global__ __launch_bounds__(256)
void qkv_proj_kernel(const float* __restrict__ x,
                     const float* __restrict__ Wk,
                     const float* __restrict__ Wq,
                     const float* __restrict__ Wv,
                     float* __restrict__ q,
                     float* __restrict__ k,
                     float* __restrict__ v)
{
    __shared__ __align__(16) float Xs[32][68];   // [kk][m], pad 68 -> aligned b128 rows
    __shared__ __align__(16) float Ws[32][68];   // [kk][h]

    const int which = blockIdx.y;  // 0=q, 1=k, 2=v
    const float* __restrict__ W = (which == 0) ? Wq : (which == 1) ? Wk : Wv;
    float* __restrict__ outp    = (which == 0) ? q  : (which == 1) ? k  : v;

    const int m_base = blockIdx.x * 64;
    const int tid = threadIdx.x;
    const int tx = tid & 15;      // -> h0 = tx*4
    const int ty = tid >> 4;      // -> m0 = ty*4

    float acc[4][4] = {};

    for (int k0 = 0; k0 < CC; k0 += 32) {
        // load 64x32 X tile and 64x32 W tile, transposed into LDS
        #pragma unroll
        for (int ld = 0; ld < 2; ++ld) {
            const int s    = tid + ld * 256;   // 0..511
            const int row  = s >> 3;           // 0..63
            const int c4   = (s & 7) * 4;      // 0..28
            const float4 xv = *reinterpret_cast<const float4*>(
                &x[(size_t)(m_base + row) * CC + k0 + c4]);
            Xs[c4 + 0][row] = xv.x;
            Xs[c4 + 1][row] = xv.y;
            Xs[c4 + 2][row] = xv.z;
            Xs[c4 + 3][row] = xv.w;
            const float4 wv = *reinterpret_cast<const float4*>(
                &W[(size_t)row * CC + k0 + c4]);
            Ws[c4 + 0][row] = wv.x;
            Ws[c4 + 1][row] = wv.y;
            Ws[c4 + 2][row] = wv.z;
            Ws[c4 + 3][row] = wv.w;
        }
        __syncthreads();

        #pragma unroll 8
        for (int kk = 0; kk < 32; ++kk) {
            const float4 a = *reinterpret_cast<const float4*>(&Xs[kk][ty * 4]);
            const float4 b = *reinterpret_cast<const float4*>(&Ws[kk][tx * 4]);
            const float av[4] = {a.x, a.y, a.z, a.w};
            const float bv[4] = {b.x, b.y, b.z, b.w};
            #pragma unroll
            for (int i = 0; i < 4; ++i)
                #pragma unroll
                for (int j = 0; j < 4; ++j)
                    acc[i][j] += av[i] * bv[j];
        }
        __syncthreads();
    }

    #pragma unroll
    for (int i = 0; i < 4; ++i) {
        const float4 o = make_float4(acc[i][0], acc[i][1], acc[i][2], acc[i][3]);
        *reinterpret_cast<float4*>(
            &outp[(size_t)(m_base + ty * 4 + i) * HH + tx * 4]) = o;
    }
}

// ---------------------------------------------------------------------------
// Kernel 2: fused causal attention with online softmax (flash-style).
// One block = (batch b, 32-row Q tile). Key tiles of 64. 256 threads (16x16):
// per-thread S tile 2 rows x 4 cols; O accumulator 2x4 (h = tx*4).
// Blocks launched longest-first (i-tile descending) for load balance.
// wei = (q . k) * 8.0  (reference MULTIPLIES by sqrt(H)=8)
// ---------------------------------------------------------------------------
__global__ __launch_bounds__(256)
void attn_kernel(const float* __restrict__ q,
                 const float* __restrict__ k,
                 const float* __restrict__ v,
                 float* __restrict__ out)
{
    __shared__ __align__(16) float Qt[64][36];   // [kk][m]  32 q rows
    __shared__ __align__(16) float Kt[64][68];   // [kk][n]  64 keys
    __shared__ __align__(16) float Vs[64][68];   // [n][h]
    __shared__ __align__(16) float Pt[64][36];   // [n][m]

    const int bid = blockIdx.x;
    const int b = bid & 7;
    const int itile = 63 - (bid >> 3);       // descending work order
    const int row_base = itile * 32;

    const int tid = threadIdx.x;
    const int tx = tid & 15;
    const int ty = tid >> 4;
    const int m0 = ty * 2;                   // 2 rows per thread
    const int n0 = tx * 4;                   // 4 cols (keys / h) per thread

    const float* __restrict__ qb = q + (size_t)b * TT * HH;
    const float* __restrict__ kb = k + (size_t)b * TT * HH;
    const float* __restrict__ vb = v + (size_t)b * TT * HH;

    // load Q tile (32 x 64) transposed into Qt[kk][m]
    #pragma unroll
    for (int ld = 0; ld < 2; ++ld) {
        const int s   = tid + ld * 256;      // 0..511
        const int mr  = s >> 4;              // 0..31
        const int h4  = (s & 15) * 4;        // 0..60
        const float4 qv = *reinterpret_cast<const float4*>(
            &qb[(size_t)(row_base + mr) * HH + h4]);
        Qt[h4 + 0][mr] = qv.x;
        Qt[h4 + 1][mr] = qv.y;
        Qt[h4 + 2][mr] = qv.z;
        Qt[h4 + 3][mr] = qv.w;
    }

    float O[2][4] = {};
    float mrun[2] = {-3.0e38f, -3.0e38f};
    float lrun[2] = {0.0f, 0.0f};

    const int jmax = (row_base + 31) >> 6;
    for (int j = 0; j <= jmax; ++j) {
        // load K,V tiles (64 keys x 64 h); K transposed, V natural
        #pragma unroll
        for (int ld = 0; ld < 4; ++ld) {
            const int s  = tid + ld * 256;   // 0..1023
            const int tr = s >> 4;           // 0..63
            const int h4 = (s & 15) * 4;
            const float4 kv = *reinterpret_cast<const float4*>(
                &kb[(size_t)(j * 64 + tr) * HH + h4]);
            Kt[h4 + 0][tr] = kv.x;
            Kt[h4 + 1][tr] = kv.y;
            Kt[h4 + 2][tr] = kv.z;
            Kt[h4 + 3][tr] = kv.w;
            const float4 vv = *reinterpret_cast<const float4*>(
                &vb[(size_t)(j * 64 + tr) * HH + h4]);
            *reinterpret_cast<float4*>(&Vs[tr][h4]) = vv;
        }
        __syncthreads();

        // S = Q @ K^T
        float s_acc[2][4] = {};
        #pragma unroll 8
        for (int kk = 0; kk < 64; ++kk) {
            const float2 a = *reinterpret_cast<const float2*>(&Qt[kk][m0]);
            const float4 bv = *reinterpret_cast<const float4*>(&Kt[kk][n0]);
            s_acc[0][0] += a.x * bv.x; s_acc[0][1] += a.x * bv.y;
            s_acc[0][2] += a.x * bv.z; s_acc[0][3] += a.x * bv.w;
            s_acc[1][0] += a.y * bv.x; s_acc[1][1] += a.y * bv.y;
            s_acc[1][2] += a.y * bv.z; s_acc[1][3] += a.y * bv.w;
        }

        // scale by sqrt(H)=8 and apply causal mask
        #pragma unroll
        for (int rr = 0; rr < 2; ++rr) {
            const int row = row_base + m0 + rr;
            #pragma unroll
            for (int cc = 0; cc < 4; ++cc) {
                const int col = j * 64 + n0 + cc;
                s_acc[rr][cc] = (col <= row) ? s_acc[rr][cc] * 8.0f : -1.0e30f;
            }
        }

        // online softmax update (row reductions across the 16 tx lanes)
        float p[2][4];
        #pragma unroll
        for (int rr = 0; rr < 2; ++rr) {
            float rmax = fmaxf(fmaxf(s_acc[rr][0], s_acc[rr][1]),
                               fmaxf(s_acc[rr][2], s_acc[rr][3]));
            #pragma unroll
            for (int off = 1; off < 16; off <<= 1)
                rmax = fmaxf(rmax, __shfl_xor(rmax, off, 16));
            const float mnew = fmaxf(mrun[rr], rmax);
            const float sc = __expf(mrun[rr] - mnew);
            float rsum = 0.0f;
            #pragma unroll
            for (int cc = 0; cc < 4; ++cc) {
                p[rr][cc] = __expf(s_acc[rr][cc] - mnew);
                rsum += p[rr][cc];
            }
            #pragma unroll
            for (int off = 1; off < 16; off <<= 1)
                rsum += __shfl_xor(rsum, off, 16);
            lrun[rr] = lrun[rr] * sc + rsum;
            #pragma unroll
            for (int cc = 0; cc < 4; ++cc)
                O[rr][cc] *= sc;
            mrun[rr] = mnew;
        }

        // write P transposed for PV
        #pragma unroll
        for (int rr = 0; rr < 2; ++rr)
            #pragma unroll
            for (int cc = 0; cc < 4; ++cc)
                Pt[n0 + cc][m0 + rr] = p[rr][cc];
        __syncthreads();

        // O += P @ V
        #pragma unroll 8
        for (int n = 0; n < 64; ++n) {
            const float2 pv = *reinterpret_cast<const float2*>(&Pt[n][m0]);
            const float4 vv = *reinterpret_cast<const float4*>(&Vs[n][n0]);
            O[0][0] += pv.x * vv.x; O[0][1] += pv.x * vv.y;
            O[0][2] += pv.x * vv.z; O[0][3] += pv.x * vv.w;
            O[1][0] += pv.y * vv.x; O[1][1] += pv.y * vv.y;
            O[1][2] += pv.y * vv.z; O[1][3] += pv.y * vv.w;
        }
        __syncthreads();   // before next tile overwrites Kt/Vs/Pt
    }

    // epilogue: out = O / l
    const float inv0 = 1.0f / lrun[0];
    const float inv1 = 1.0f / lrun[1];
    const float4 o0 = make_float4(O[0][0] * inv0, O[0][1] * inv0,
                                  O[0][2] * inv0, O[0][3] * inv0);
    const float4 o1 = make_float4(O[1][0] * inv1, O[1][1] * inv1,
                                  O[1][2] * inv1, O[1][3] * inv1);
    *reinterpret_cast<float4*>(
        &out[(size_t)(b * TT + row_base + m0 + 0) * HH + n0]) = o0;
    *reinterpret_cast<float4*>(
        &out[(size_t)(b * TT + row_base + m0 + 1) * HH + n0]) = o1;
}

// ---------------------------------------------------------------------------
extern "C" void kernel_launch(void* const* d_in, const int* in_sizes, int n_in,
                              void* d_out, int out_size, void* d_ws, size_t ws_size,
                              hipStream_t stream)
{
    (void)in_sizes; (void)n_in; (void)out_size; (void)ws_size;

    const float* x  = (const float*)d_in[0];
    const float* Wk = (const float*)d_in[1];
    const float* Wq = (const float*)d_in[2];
    const float* Wv = (const float*)d_in[3];
    float* out = (float*)d_out;

    float* q = (float*)d_ws;                       // [MM][HH]
    float* k = q + (size_t)MM * HH;                // [MM][HH]
    float* v = k + (size_t)MM * HH;                // [MM][HH]

    dim3 pgrid(MM / 64, 3);
    qkv_proj_kernel<<<pgrid, dim3(256), 0, stream>>>(x, Wk, Wq, Wv, q, k, v);
    attn_kernel<<<dim3(512), dim3(256), 0, stream>>>(q, k, v, out);
}

// Round 2
// 188.873 us; speedup vs baseline: 1.7284x; 1.7284x over previous
//
#include <hip/hip_runtime.h>

#define BB 8
#define TT 2048
#define CC 1024
#define HH 64
#define MM (BB * TT)   // 16384 rows

typedef _Float16 half8 __attribute__((ext_vector_type(8)));
typedef float floatx4 __attribute__((ext_vector_type(4)));

// ---------------------------------------------------------------------------
// Kernel 1: QKV projection with fp16 MFMA.  out[m,h] = sum_c x[m,c]*W[h,c]
// grid = (MM/64, 3): y selects (q,k,v). Block 256 = 4 waves, M-tile 64,
// N = 64 (all of H). fp32->fp16 conversion fused into LDS staging.
// q is stored pre-scaled by 8 (= sqrt(H), reference multiplies).
// LDS stride 40 halves = 80 B -> 2-way bank aliasing (free).
// ---------------------------------------------------------------------------
__global__ __launch_bounds__(256, 4)
void qkv_proj(const float* __restrict__ x,  const float* __restrict__ Wk,
              const float* __restrict__ Wq, const float* __restrict__ Wv,
              _Float16* __restrict__ q16, _Float16* __restrict__ k16,
              _Float16* __restrict__ v16)
{
    __shared__ _Float16 Xs[64 * 40];
    __shared__ _Float16 Ws[64 * 40];

    const int which = blockIdx.y;
    const float* __restrict__ W = (which == 0) ? Wq : ((which == 1) ? Wk : Wv);
    _Float16* __restrict__ outp = (which == 0) ? q16 : ((which == 1) ? k16 : v16);
    const float oscale = (which == 0) ? 8.0f : 1.0f;

    const int m_base = blockIdx.x * 64;
    const int tid  = threadIdx.x;
    const int lane = tid & 63;
    const int wv   = tid >> 6;
    const int fm   = lane & 15;         // A/B fragment row
    const int fk   = (lane >> 4) * 8;   // fragment k offset (halves)
    const int fr   = (lane >> 4) * 4;   // C fragment row base

    const int srow = tid >> 2;          // staging row 0..63
    const int skq  = (tid & 3) * 8;     // staging k offset 0..24

    floatx4 acc[4];
    #pragma unroll
    for (int nt = 0; nt < 4; ++nt)
        #pragma unroll
        for (int r = 0; r < 4; ++r) acc[nt][r] = 0.0f;

    for (int k0 = 0; k0 < CC; k0 += 32) {
        const float* xs = &x[(size_t)(m_base + srow) * CC + k0 + skq];
        const float4 xa = *reinterpret_cast<const float4*>(xs);
        const float4 xb = *reinterpret_cast<const float4*>(xs + 4);
        const float* wsrc = &W[(size_t)srow * CC + k0 + skq];
        const float4 wa = *reinterpret_cast<const float4*>(wsrc);
        const float4 wb = *reinterpret_cast<const float4*>(wsrc + 4);
        const half8 hx = { (_Float16)xa.x, (_Float16)xa.y, (_Float16)xa.z, (_Float16)xa.w,
                           (_Float16)xb.x, (_Float16)xb.y, (_Float16)xb.z, (_Float16)xb.w };
        const half8 hw = { (_Float16)wa.x, (_Float16)wa.y, (_Float16)wa.z, (_Float16)wa.w,
                           (_Float16)wb.x, (_Float16)wb.y, (_Float16)wb.z, (_Float16)wb.w };

        __syncthreads();   // protect previous iteration's LDS reads
        *reinterpret_cast<half8*>(&Xs[srow * 40 + skq]) = hx;
        *reinterpret_cast<half8*>(&Ws[srow * 40 + skq]) = hw;
        __syncthreads();

        const half8 af = *reinterpret_cast<const half8*>(&Xs[(wv * 16 + fm) * 40 + fk]);
        #pragma unroll
        for (int nt = 0; nt < 4; ++nt) {
            const half8 bf = *reinterpret_cast<const half8*>(&Ws[(nt * 16 + fm) * 40 + fk]);
            acc[nt] = __builtin_amdgcn_mfma_f32_16x16x32_f16(af, bf, acc[nt], 0, 0, 0);
        }
    }

    // epilogue: C/D layout row = fr + r, col = nt*16 + fm
    #pragma unroll
    for (int nt = 0; nt < 4; ++nt)
        #pragma unroll
        for (int r = 0; r < 4; ++r)
            outp[(size_t)(m_base + wv * 16 + fr + r) * HH + nt * 16 + fm] =
                (_Float16)(acc[nt][r] * oscale);
}

// ---------------------------------------------------------------------------
// Kernel 2: transpose v[b][t][h] -> vt[b][h][t] (fp16), 64x64 tiles.
// ---------------------------------------------------------------------------
__global__ __launch_bounds__(256, 4)
void v_transpose(const _Float16* __restrict__ v16, _Float16* __restrict__ vt16)
{
    __shared__ _Float16 Ts[64 * 72];
    const int bid = blockIdx.x;
    const int b = bid >> 5, tile = bid & 31;
    const int tid = threadIdx.x;

    #pragma unroll
    for (int i = 0; i < 2; ++i) {
        const int s = i * 256 + tid;
        const int row = s >> 3, cq = (s & 7) * 8;
        *reinterpret_cast<half8*>(&Ts[row * 72 + cq]) =
            *reinterpret_cast<const half8*>(&v16[((size_t)b * TT + tile * 64 + row) * HH + cq]);
    }
    __syncthreads();
    #pragma unroll
    for (int i = 0; i < 2; ++i) {
        const int s = i * 256 + tid;
        const int h = s >> 3, tq = (s & 7) * 8;
        half8 o;
        #pragma unroll
        for (int jj = 0; jj < 8; ++jj) o[jj] = Ts[(tq + jj) * 72 + h];
        *reinterpret_cast<half8*>(&vt16[((size_t)b * HH + h) * TT + tile * 64 + tq]) = o;
    }
}

// ---------------------------------------------------------------------------
// Kernel 3: fused causal attention, fp16 MFMA, online softmax.
// grid = 256 (b x 32 q-tiles of 64 rows, longest-first). Block 256 = 4 waves,
// wave = 16-row group. j-tiles of 64 keys. Q A-frags persistent in VGPRs.
// S frags (C-layout) -> width-16 shfl softmax -> P via LDS (A-layout) -> PV.
// LDS strides 72 halves = 144 B -> 2-way bank aliasing (free).
// Scale *8 already folded into q16. Only diagonal j-tile needs masking.
// ---------------------------------------------------------------------------
__global__ __launch_bounds__(256, 2)
void attn(const _Float16* __restrict__ q16, const _Float16* __restrict__ k16,
          const _Float16* __restrict__ vt16, float* __restrict__ out)
{
    __shared__ _Float16 Ks[64 * 72];
    __shared__ _Float16 Vts[64 * 72];
    __shared__ _Float16 Ps[4 * 16 * 72];

    const int bid = blockIdx.x;
    const int b = bid & 7;
    const int itile = 31 - (bid >> 3);      // longest blocks first
    const int tid  = threadIdx.x;
    const int lane = tid & 63;
    const int wv   = tid >> 6;
    const int fm   = lane & 15;
    const int fk   = (lane >> 4) * 8;
    const int fr   = (lane >> 4) * 4;

    const _Float16* __restrict__ qb  = q16  + (size_t)b * TT * HH;
    const _Float16* __restrict__ kb  = k16  + (size_t)b * TT * HH;
    const _Float16* __restrict__ vtb = vt16 + (size_t)b * HH * TT;

    const int qrow = itile * 64 + wv * 16 + fm;
    const half8 qf0 = *reinterpret_cast<const half8*>(&qb[(size_t)qrow * HH + fk]);
    const half8 qf1 = *reinterpret_cast<const half8*>(&qb[(size_t)qrow * HH + 32 + fk]);

    floatx4 O[4];
    float m_r[4], l_r[4];
    #pragma unroll
    for (int r = 0; r < 4; ++r) {
        m_r[r] = -3.0e38f;
        l_r[r] = 0.0f;
        #pragma unroll
        for (int ht = 0; ht < 4; ++ht) O[ht][r] = 0.0f;
    }

    // staging coords: 512 16B-chunks over 2 iters
    const int sr = tid >> 3;          // 0..31
    const int sc = (tid & 7) * 8;     // 0..56

    for (int j = 0; j <= itile; ++j) {
        // ---- stage K tile [key][h] and Vt tile [h][key] ----
        const half8 kv0 = *reinterpret_cast<const half8*>(&kb[(size_t)(j * 64 + sr) * HH + sc]);
        const half8 kv1 = *reinterpret_cast<const half8*>(&kb[(size_t)(j * 64 + sr + 32) * HH + sc]);
        const half8 vv0 = *reinterpret_cast<const half8*>(&vtb[(size_t)sr * TT + j * 64 + sc]);
        const half8 vv1 = *reinterpret_cast<const half8*>(&vtb[(size_t)(sr + 32) * TT + j * 64 + sc]);
        __syncthreads();   // previous iteration's LDS reads done
        *reinterpret_cast<half8*>(&Ks[sr * 72 + sc])          = kv0;
        *reinterpret_cast<half8*>(&Ks[(sr + 32) * 72 + sc])   = kv1;
        *reinterpret_cast<half8*>(&Vts[sr * 72 + sc])         = vv0;
        *reinterpret_cast<half8*>(&Vts[(sr + 32) * 72 + sc])  = vv1;
        __syncthreads();

        // ---- S = Q K^T : 8 MFMAs ----
        floatx4 sa[4];
        #pragma unroll
        for (int nt = 0; nt < 4; ++nt) {
            #pragma unroll
            for (int r = 0; r < 4; ++r) sa[nt][r] = 0.0f;
            const _Float16* kp = &Ks[(nt * 16 + fm) * 72];
            const half8 b0 = *reinterpret_cast<const half8*>(kp + fk);
            const half8 b1 = *reinterpret_cast<const half8*>(kp + 32 + fk);
            sa[nt] = __builtin_amdgcn_mfma_f32_16x16x32_f16(qf0, b0, sa[nt], 0, 0, 0);
            sa[nt] = __builtin_amdgcn_mfma_f32_16x16x32_f16(qf1, b1, sa[nt], 0, 0, 0);
        }

        // ---- causal mask (only the diagonal tile) ----
        if (j == itile) {
            #pragma unroll
            for (int nt = 0; nt < 4; ++nt)
                #pragma unroll
                for (int r = 0; r < 4; ++r)
                    if (nt * 16 + fm > wv * 16 + fr + r) sa[nt][r] = -3.0e38f;
        }

        // ---- online softmax (rows live in 16-lane groups) ----
        #pragma unroll
        for (int r = 0; r < 4; ++r) {
            float mx = fmaxf(fmaxf(sa[0][r], sa[1][r]), fmaxf(sa[2][r], sa[3][r]));
            #pragma unroll
            for (int off = 1; off < 16; off <<= 1)
                mx = fmaxf(mx, __shfl_xor(mx, off, 16));
            const float mn = fmaxf(m_r[r], mx);
            const float alpha = __expf(m_r[r] - mn);
            const float p0 = __expf(sa[0][r] - mn);
            const float p1 = __expf(sa[1][r] - mn);
            const float p2 = __expf(sa[2][r] - mn);
            const float p3 = __expf(sa[3][r] - mn);
            _Float16* pp = &Ps[wv * 1152 + (fr + r) * 72 + fm];
            pp[0]  = (_Float16)p0;
            pp[16] = (_Float16)p1;
            pp[32] = (_Float16)p2;
            pp[48] = (_Float16)p3;
            float sum = p0 + p1 + p2 + p3;
            #pragma unroll
            for (int off = 1; off < 16; off <<= 1)
                sum += __shfl_xor(sum, off, 16);
            l_r[r] = l_r[r] * alpha + sum;
            m_r[r] = mn;
            O[0][r] *= alpha; O[1][r] *= alpha; O[2][r] *= alpha; O[3][r] *= alpha;
        }
        __syncthreads();   // P visible (and ordered) before A-frag reads

        // ---- O += P V : 8 MFMAs ----
        #pragma unroll
        for (int ch = 0; ch < 2; ++ch) {
            const half8 pa = *reinterpret_cast<const half8*>(
                &Ps[wv * 1152 + fm * 72 + ch * 32 + fk]);
            #pragma unroll
            for (int ht = 0; ht < 4; ++ht) {
                const half8 vb = *reinterpret_cast<const half8*>(
                    &Vts[(ht * 16 + fm) * 72 + ch * 32 + fk]);
                O[ht] = __builtin_amdgcn_mfma_f32_16x16x32_f16(pa, vb, O[ht], 0, 0, 0);
            }
        }
    }

    // ---- epilogue: out = O / l (fp32) ----
    #pragma unroll
    for (int r = 0; r < 4; ++r) {
        const float inv = 1.0f / l_r[r];
        const size_t rowoff = (size_t)(b * TT + itile * 64 + wv * 16 + fr + r) * HH;
        #pragma unroll
        for (int ht = 0; ht < 4; ++ht)
            out[rowoff + ht * 16 + fm] = O[ht][r] * inv;
    }
}

// ---------------------------------------------------------------------------
extern "C" void kernel_launch(void* const* d_in, const int* in_sizes, int n_in,
                              void* d_out, int out_size, void* d_ws, size_t ws_size,
                              hipStream_t stream)
{
    (void)in_sizes; (void)n_in; (void)out_size; (void)ws_size;

    const float* x  = (const float*)d_in[0];
    const float* Wk = (const float*)d_in[1];
    const float* Wq = (const float*)d_in[2];
    const float* Wv = (const float*)d_in[3];
    float* out = (float*)d_out;

    _Float16* q16  = (_Float16*)d_ws;                     // [MM][HH]
    _Float16* k16  = q16 + (size_t)MM * HH;               // [MM][HH]
    _Float16* v16  = k16 + (size_t)MM * HH;               // [MM][HH]
    _Float16* vt16 = v16 + (size_t)MM * HH;               // [BB][HH][TT]

    qkv_proj<<<dim3(MM / 64, 3), dim3(256), 0, stream>>>(x, Wk, Wq, Wv, q16, k16, v16);
    v_transpose<<<dim3(256), dim3(256), 0, stream>>>(v16, vt16);
    attn<<<dim3(256), dim3(256), 0, stream>>>(q16, k16, vt16, out);
}

// Round 3
// 177.312 us; speedup vs baseline: 1.8410x; 1.0652x over previous
//
#include <hip/hip_runtime.h>

#define BB 8
#define TT 2048
#define CC 1024
#define HH 64
#define MM (BB * TT)   // 16384 rows

typedef _Float16 half8 __attribute__((ext_vector_type(8)));
typedef float floatx4 __attribute__((ext_vector_type(4)));

// ---------------------------------------------------------------------------
// Kernel 0: pack W -> fp16 W16[192][1024]; rows 0..63 = Wq * 8 (sqrt(H) fold),
// 64..127 = Wk, 128..191 = Wv.  grid 96 x 256, 8 elems/thread.
// ---------------------------------------------------------------------------
__global__ __launch_bounds__(256)
void w_convert(const float* __restrict__ Wk, const float* __restrict__ Wq,
               const float* __restrict__ Wv, _Float16* __restrict__ W16)
{
    const int e = (blockIdx.x * 256 + threadIdx.x) * 8;
    const int row = e >> 10;            // 0..191
    const int c   = e & 1023;
    const int which = row >> 6;
    const float* __restrict__ src = (which == 0) ? Wq : ((which == 1) ? Wk : Wv);
    const float scale = (which == 0) ? 8.0f : 1.0f;
    const int srow = row & 63;
    const float4 a = *reinterpret_cast<const float4*>(&src[srow * 1024 + c]);
    const float4 b = *reinterpret_cast<const float4*>(&src[srow * 1024 + c + 4]);
    const half8 o = { (_Float16)(a.x * scale), (_Float16)(a.y * scale),
                      (_Float16)(a.z * scale), (_Float16)(a.w * scale),
                      (_Float16)(b.x * scale), (_Float16)(b.y * scale),
                      (_Float16)(b.z * scale), (_Float16)(b.w * scale) };
    *reinterpret_cast<half8*>(&W16[e]) = o;
}

// ---------------------------------------------------------------------------
// Kernel 1: fused QKV projection. One pass over x: out[m, 0:192] = x @ W16^T.
// grid 256 (M-tile 64), block 256 = 4 waves; wave wv -> n-tiles [3wv, 3wv+3).
// K-chunk 64, software prefetch (next chunk's global loads issued before
// current chunk's MFMAs). LDS stride 72 halves -> 2-way bank alias (free).
// ---------------------------------------------------------------------------
__global__ __launch_bounds__(256, 2)
void qkv_fused(const float* __restrict__ x, const _Float16* __restrict__ W16,
               _Float16* __restrict__ q16, _Float16* __restrict__ k16,
               _Float16* __restrict__ v16)
{
    __shared__ _Float16 Xs[64 * 72];
    __shared__ _Float16 Ws[192 * 72];

    const int m_base = blockIdx.x * 64;
    const int tid  = threadIdx.x;
    const int lane = tid & 63;
    const int wv   = tid >> 6;
    const int fm   = lane & 15;
    const int fk   = (lane >> 4) * 8;
    const int fr   = (lane >> 4) * 4;

    // staging coords
    const int srow = tid >> 2;          // 0..63
    const int sk   = (tid & 3) * 16;    // 0,16,32,48

    floatx4 acc[4][3];
    #pragma unroll
    for (int m = 0; m < 4; ++m)
        #pragma unroll
        for (int n = 0; n < 3; ++n)
            #pragma unroll
            for (int r = 0; r < 4; ++r) acc[m][n][r] = 0.0f;

    float4 xr[4];
    half8  wr[6];

    // prologue: loads for chunk 0
    {
        const float* xp = &x[(size_t)(m_base + srow) * CC + sk];
        #pragma unroll
        for (int i = 0; i < 4; ++i) xr[i] = *reinterpret_cast<const float4*>(xp + i * 4);
        #pragma unroll
        for (int i = 0; i < 6; ++i) {
            const int cch = tid + i * 256;            // 0..1535
            const int wrow = cch >> 3, wk = (cch & 7) * 8;
            wr[i] = *reinterpret_cast<const half8*>(&W16[(size_t)wrow * CC + wk]);
        }
    }

    for (int c = 0; c < 16; ++c) {
        __syncthreads();   // prior chunk's LDS reads complete
        // store staged regs to LDS (fp32 -> fp16 for x)
        #pragma unroll
        for (int p = 0; p < 2; ++p) {
            const float4 a = xr[p * 2], b = xr[p * 2 + 1];
            const half8 h = { (_Float16)a.x, (_Float16)a.y, (_Float16)a.z, (_Float16)a.w,
                              (_Float16)b.x, (_Float16)b.y, (_Float16)b.z, (_Float16)b.w };
            *reinterpret_cast<half8*>(&Xs[srow * 72 + sk + p * 8]) = h;
        }
        #pragma unroll
        for (int i = 0; i < 6; ++i) {
            const int cch = tid + i * 256;
            const int wrow = cch >> 3, wk = (cch & 7) * 8;
            *reinterpret_cast<half8*>(&Ws[wrow * 72 + wk]) = wr[i];
        }
        __syncthreads();

        // prefetch next chunk
        if (c < 15) {
            const int k0 = (c + 1) * 64;
            const float* xp = &x[(size_t)(m_base + srow) * CC + k0 + sk];
            #pragma unroll
            for (int i = 0; i < 4; ++i) xr[i] = *reinterpret_cast<const float4*>(xp + i * 4);
            #pragma unroll
            for (int i = 0; i < 6; ++i) {
                const int cch = tid + i * 256;
                const int wrow = cch >> 3, wk = (cch & 7) * 8;
                wr[i] = *reinterpret_cast<const half8*>(&W16[(size_t)wrow * CC + k0 + wk]);
            }
        }

        // compute: 2 k-sub-chunks x (4 m-tiles x 3 n-tiles)
        #pragma unroll
        for (int kc = 0; kc < 2; ++kc) {
            half8 af[4];
            #pragma unroll
            for (int m = 0; m < 4; ++m)
                af[m] = *reinterpret_cast<const half8*>(&Xs[(m * 16 + fm) * 72 + kc * 32 + fk]);
            #pragma unroll
            for (int n = 0; n < 3; ++n) {
                const half8 bf = *reinterpret_cast<const half8*>(
                    &Ws[((wv * 3 + n) * 16 + fm) * 72 + kc * 32 + fk]);
                #pragma unroll
                for (int m = 0; m < 4; ++m)
                    acc[m][n] = __builtin_amdgcn_mfma_f32_16x16x32_f16(af[m], bf, acc[m][n], 0, 0, 0);
            }
        }
    }

    // epilogue: col = (wv*3+n)*16 + fm selects q/k/v
    #pragma unroll
    for (int n = 0; n < 3; ++n) {
        const int col = (wv * 3 + n) * 16 + fm;
        const int which = col >> 6;
        const int h = col & 63;
        _Float16* __restrict__ outp = (which == 0) ? q16 : ((which == 1) ? k16 : v16);
        #pragma unroll
        for (int m = 0; m < 4; ++m)
            #pragma unroll
            for (int r = 0; r < 4; ++r)
                outp[(size_t)(m_base + m * 16 + fr + r) * HH + h] = (_Float16)acc[m][n][r];
    }
}

// ---------------------------------------------------------------------------
// Kernel 2: transpose v[b][t][h] -> vt[b][h][t] (fp16), 64x64 tiles.
// ---------------------------------------------------------------------------
__global__ __launch_bounds__(256, 4)
void v_transpose(const _Float16* __restrict__ v16, _Float16* __restrict__ vt16)
{
    __shared__ _Float16 Ts[64 * 72];
    const int bid = blockIdx.x;
    const int b = bid >> 5, tile = bid & 31;
    const int tid = threadIdx.x;

    #pragma unroll
    for (int i = 0; i < 2; ++i) {
        const int s = i * 256 + tid;
        const int row = s >> 3, cq = (s & 7) * 8;
        *reinterpret_cast<half8*>(&Ts[row * 72 + cq]) =
            *reinterpret_cast<const half8*>(&v16[((size_t)b * TT + tile * 64 + row) * HH + cq]);
    }
    __syncthreads();
    #pragma unroll
    for (int i = 0; i < 2; ++i) {
        const int s = i * 256 + tid;
        const int h = s >> 3, tq = (s & 7) * 8;
        half8 o;
        #pragma unroll
        for (int jj = 0; jj < 8; ++jj) o[jj] = Ts[(tq + jj) * 72 + h];
        *reinterpret_cast<half8*>(&vt16[((size_t)b * HH + h) * TT + tile * 64 + tq]) = o;
    }
}

// ---------------------------------------------------------------------------
// Kernel 3: fused causal attention, fp16 MFMA, online softmax.
// grid 512 = 8 batches x 64 q-tiles of 32 rows (longest-first). Block 128 =
// 2 waves, wave = 16-row group. j-tiles of 64 keys, Ji = (it>>1)+1.
// K/V tiles prefetched into regs one j-tile ahead. LDS 20.7 KB -> multi-block
// co-residency; 512 blocks / 256 CUs -> makespan ~ total/256 (balanced).
// ---------------------------------------------------------------------------
__global__ __launch_bounds__(128, 4)
void attn(const _Float16* __restrict__ q16, const _Float16* __restrict__ k16,
          const _Float16* __restrict__ vt16, float* __restrict__ out)
{
    __shared__ _Float16 Ks[64 * 72];
    __shared__ _Float16 Vts[64 * 72];
    __shared__ _Float16 Ps[2 * 16 * 72];

    const int bid = blockIdx.x;
    const int b  = bid & 7;
    const int it = 63 - (bid >> 3);         // longest blocks first
    const int tid  = threadIdx.x;
    const int lane = tid & 63;
    const int wv   = tid >> 6;              // 0,1
    const int fm   = lane & 15;
    const int fk   = (lane >> 4) * 8;
    const int fr   = (lane >> 4) * 4;

    const _Float16* __restrict__ qb  = q16  + (size_t)b * TT * HH;
    const _Float16* __restrict__ kb  = k16  + (size_t)b * TT * HH;
    const _Float16* __restrict__ vtb = vt16 + (size_t)b * HH * TT;

    const int qrow = it * 32 + wv * 16 + fm;
    const half8 qf0 = *reinterpret_cast<const half8*>(&qb[(size_t)qrow * HH + fk]);
    const half8 qf1 = *reinterpret_cast<const half8*>(&qb[(size_t)qrow * HH + 32 + fk]);

    floatx4 O[4];
    float m_r[4], l_r[4];
    #pragma unroll
    for (int r = 0; r < 4; ++r) {
        m_r[r] = -3.0e38f; l_r[r] = 0.0f;
        #pragma unroll
        for (int ht = 0; ht < 4; ++ht) O[ht][r] = 0.0f;
    }

    const int Ji = (it >> 1) + 1;
    const int sr = tid >> 3;          // 0..15
    const int sc = (tid & 7) * 8;     // 0..56

    half8 kr[4], vr[4];
    // prologue: prefetch j=0
    #pragma unroll
    for (int i = 0; i < 4; ++i) {
        kr[i] = *reinterpret_cast<const half8*>(&kb[(size_t)(sr + i * 16) * HH + sc]);
        vr[i] = *reinterpret_cast<const half8*>(&vtb[(size_t)(sr + i * 16) * TT + sc]);
    }

    for (int j = 0; j < Ji; ++j) {
        __syncthreads();   // prior iteration's LDS reads complete
        #pragma unroll
        for (int i = 0; i < 4; ++i) {
            *reinterpret_cast<half8*>(&Ks[(sr + i * 16) * 72 + sc])  = kr[i];
            *reinterpret_cast<half8*>(&Vts[(sr + i * 16) * 72 + sc]) = vr[i];
        }
        __syncthreads();

        // prefetch next j-tile
        if (j + 1 < Ji) {
            const int jn = (j + 1) * 64;
            #pragma unroll
            for (int i = 0; i < 4; ++i) {
                kr[i] = *reinterpret_cast<const half8*>(&kb[(size_t)(jn + sr + i * 16) * HH + sc]);
                vr[i] = *reinterpret_cast<const half8*>(&vtb[(size_t)(sr + i * 16) * TT + jn + sc]);
            }
        }

        // ---- S = Q K^T : 8 MFMAs ----
        floatx4 sa[4];
        #pragma unroll
        for (int nt = 0; nt < 4; ++nt) {
            #pragma unroll
            for (int r = 0; r < 4; ++r) sa[nt][r] = 0.0f;
            const _Float16* kp = &Ks[(nt * 16 + fm) * 72];
            const half8 b0 = *reinterpret_cast<const half8*>(kp + fk);
            const half8 b1 = *reinterpret_cast<const half8*>(kp + 32 + fk);
            sa[nt] = __builtin_amdgcn_mfma_f32_16x16x32_f16(qf0, b0, sa[nt], 0, 0, 0);
            sa[nt] = __builtin_amdgcn_mfma_f32_16x16x32_f16(qf1, b1, sa[nt], 0, 0, 0);
        }

        // ---- causal mask (only diagonal j-tile) ----
        if (j == Ji - 1) {
            const int rbase = it * 32 + wv * 16 + fr;
            #pragma unroll
            for (int nt = 0; nt < 4; ++nt) {
                const int col = j * 64 + nt * 16 + fm;
                #pragma unroll
                for (int r = 0; r < 4; ++r)
                    if (col > rbase + r) sa[nt][r] = -3.0e38f;
            }
        }

        // ---- online softmax ----
        #pragma unroll
        for (int r = 0; r < 4; ++r) {
            float mx = fmaxf(fmaxf(sa[0][r], sa[1][r]), fmaxf(sa[2][r], sa[3][r]));
            #pragma unroll
            for (int off = 1; off < 16; off <<= 1)
                mx = fmaxf(mx, __shfl_xor(mx, off, 16));
            const float mn = fmaxf(m_r[r], mx);
            const float alpha = __expf(m_r[r] - mn);
            const float p0 = __expf(sa[0][r] - mn);
            const float p1 = __expf(sa[1][r] - mn);
            const float p2 = __expf(sa[2][r] - mn);
            const float p3 = __expf(sa[3][r] - mn);
            _Float16* pp = &Ps[wv * 1152 + (fr + r) * 72 + fm];
            pp[0]  = (_Float16)p0;
            pp[16] = (_Float16)p1;
            pp[32] = (_Float16)p2;
            pp[48] = (_Float16)p3;
            float sum = p0 + p1 + p2 + p3;
            #pragma unroll
            for (int off = 1; off < 16; off <<= 1)
                sum += __shfl_xor(sum, off, 16);
            l_r[r] = l_r[r] * alpha + sum;
            m_r[r] = mn;
            O[0][r] *= alpha; O[1][r] *= alpha; O[2][r] *= alpha; O[3][r] *= alpha;
        }
        __syncthreads();   // Ps visible before A-frag reads

        // ---- O += P V : 8 MFMAs ----
        #pragma unroll
        for (int ch = 0; ch < 2; ++ch) {
            const half8 pa = *reinterpret_cast<const half8*>(
                &Ps[wv * 1152 + fm * 72 + ch * 32 + fk]);
            #pragma unroll
            for (int ht = 0; ht < 4; ++ht) {
                const half8 vb = *reinterpret_cast<const half8*>(
                    &Vts[(ht * 16 + fm) * 72 + ch * 32 + fk]);
                O[ht] = __builtin_amdgcn_mfma_f32_16x16x32_f16(pa, vb, O[ht], 0, 0, 0);
            }
        }
    }

    // ---- epilogue ----
    #pragma unroll
    for (int r = 0; r < 4; ++r) {
        const float inv = 1.0f / l_r[r];
        const size_t rowoff = (size_t)(b * TT + it * 32 + wv * 16 + fr + r) * HH;
        #pragma unroll
        for (int ht = 0; ht < 4; ++ht)
            out[rowoff + ht * 16 + fm] = O[ht][r] * inv;
    }
}

// ---------------------------------------------------------------------------
extern "C" void kernel_launch(void* const* d_in, const int* in_sizes, int n_in,
                              void* d_out, int out_size, void* d_ws, size_t ws_size,
                              hipStream_t stream)
{
    (void)in_sizes; (void)n_in; (void)out_size; (void)ws_size;

    const float* x  = (const float*)d_in[0];
    const float* Wk = (const float*)d_in[1];
    const float* Wq = (const float*)d_in[2];
    const float* Wv = (const float*)d_in[3];
    float* out = (float*)d_out;

    _Float16* q16  = (_Float16*)d_ws;                     // [MM][HH]
    _Float16* k16  = q16 + (size_t)MM * HH;               // [MM][HH]
    _Float16* v16  = k16 + (size_t)MM * HH;               // [MM][HH]
    _Float16* vt16 = v16 + (size_t)MM * HH;               // [BB][HH][TT]
    _Float16* W16  = vt16 + (size_t)MM * HH;              // [192][1024]

    w_convert<<<dim3(96), dim3(256), 0, stream>>>(Wk, Wq, Wv, W16);
    qkv_fused<<<dim3(256), dim3(256), 0, stream>>>(x, W16, q16, k16, v16);
    v_transpose<<<dim3(256), dim3(256), 0, stream>>>(v16, vt16);
    attn<<<dim3(512), dim3(128), 0, stream>>>(q16, k16, vt16, out);
}